// Round 14
// baseline (70.553 us; speedup 1.0000x reference)
//
#include <hip/hip_runtime.h>
#include <math.h>

constexpr int H_ = 180, W_ = 320, RF_ = 16, K_ = 20, T_ = 400;
constexpr int HW_ = H_ * W_;
constexpr int NWIN = T_ - K_ + 1;   // 381
constexpr int PW   = W_ + 2 * RF_;  // 352 (padded width used by rf_indices)
constexpr float ALPHA = 50.0f, BETA = 1.0f, GAMMA = 0.0f;
constexpr int NXCD = 8;
constexpr int T_PER_XCD = T_ / NXCD;     // 50 frames per XCD
constexpr int GANG = 8;
constexpr int WPR = 36, WROWS = 32;      // padded weight table (rows -8..23)
constexpr int LDSW_W = WROWS * WPR;      // 1152 words

// ---------------------------------------------------------------------------
// VALU-pipe cross-lane primitives (proven R10/R13)
// ---------------------------------------------------------------------------
template <int CTRL>
__device__ inline float dpp_add(float v) {
    int s = __builtin_amdgcn_update_dpp(0, __float_as_int(v), CTRL, 0xF, 0xF, true);
    return v + __int_as_float(s);
}
__device__ inline float swz_xor4_add(float v) {
    return v + __int_as_float(
        __builtin_amdgcn_ds_swizzle(__float_as_int(v), 0x101F));  // lane^4
}
#if __has_builtin(__builtin_amdgcn_permlane32_swap)
__device__ inline float pl32_merge(float a, float b) {
    auto r = __builtin_amdgcn_permlane32_swap(
        __float_as_uint(a), __float_as_uint(b), false, false);
    return __uint_as_float(r[0]) + __uint_as_float(r[1]);
}
#else
__device__ inline float pl32_merge(float a, float b) {
    bool hi = (threadIdx.x & 32) != 0;
    float keep = hi ? b : a, send = hi ? a : b;
    return keep + __shfl_xor(send, 32, 64);
}
#endif
#if __has_builtin(__builtin_amdgcn_permlane16_swap)
__device__ inline float pl16_merge(float a, float b) {
    auto r = __builtin_amdgcn_permlane16_swap(
        __float_as_uint(a), __float_as_uint(b), false, false);
    return __uint_as_float(r[0]) + __uint_as_float(r[1]);
}
#else
__device__ inline float pl16_merge(float a, float b) {
    bool hi = (threadIdx.x & 16) != 0;
    float keep = hi ? b : a, send = hi ? a : b;
    return keep + __shfl_xor(send, 16, 64);
}
#endif
__device__ inline float allred64(float v) {
    v = dpp_add<0xB1>(v);    // xor 1
    v = dpp_add<0x4E>(v);    // xor 2
    v = swz_xor4_add(v);     // xor 4
    v = dpp_add<0x128>(v);   // xor 8 (row_ror:8)
    v = pl16_merge(v, v);    // xor 16
    v = pl32_merge(v, v);    // xor 32
    return v;
}
// 8-value multi-reduce: lane 8j ends holding the full wave-sum of acc[j].
__device__ inline float multired8(const float* acc, bool b8) {
    float m0 = pl32_merge(acc[0], acc[4]);
    float m1 = pl32_merge(acc[1], acc[5]);
    float m2 = pl32_merge(acc[2], acc[6]);
    float m3 = pl32_merge(acc[3], acc[7]);
    float n0 = pl16_merge(m0, m2);
    float n1 = pl16_merge(m1, m3);
    float c0v = dpp_add<0x128>(n0);
    float c1v = dpp_add<0x128>(n1);
    float C = b8 ? c1v : c0v;
    C = dpp_add<0xB1>(C);
    C = dpp_add<0x4E>(C);
    C = swz_xor4_add(C);
    return C;
}

// ---------------------------------------------------------------------------
// prep: (a) waves 0-7 factorize w (exact rank-1): row norms -> pivot ->
// temporal[K]; then all threads build the zero-padded weight table
// spat_pad[32][36]. (b) waves 8-15 build GANG tasks: consecutive neurons
// 8i..8i+7 split into runs of equal padded-row v0 (<=2 runs/gang), each run
// padded to 8 slots by repeating its last neuron. Descriptor = 3 x int4:
//   [0]: 8 x u16 neuron ids
//   [1]: 8 x u16 geometry: (c0c>>2) | ((dc+8)>>2)<<7
//   [2]: {r0c, dr, 0, 0}
// ---------------------------------------------------------------------------
__global__ __launch_bounds__(1024) void prep_kernel(
    const float* __restrict__ w, const int* __restrict__ rf,
    float* __restrict__ temporal, float* __restrict__ spat_pad,
    int* __restrict__ cnt, int4* __restrict__ tasks, int N)
{
    __shared__ float ss[32];
    int tid = threadIdx.x, wv = tid >> 6, l = tid & 63;
    if (tid == 0) *cnt = 0;
    __syncthreads();

    if (wv < 8) {
        for (int k = wv; k < K_; k += 8) {
            float s = 0.0f;
#pragma unroll
            for (int j = 0; j < 4; ++j) {
                float v = w[k * 256 + l + j * 64];
                s = fmaf(v, v, s);
            }
            s = allred64(s);
            if (l == 0) ss[k] = s;
        }
    } else {
        int ngang = (N + GANG - 1) / GANG;
        auto emit = [&](int nb, int s, int e) {   // neurons nb+s .. nb+e-1
            int idx[GANG];
#pragma unroll
            for (int j = 0; j < GANG; ++j) idx[j] = nb + min(s + j, e - 1);
            int base0 = rf[idx[0] * 256];
            int v0 = base0 / PW;
            int r0 = v0 - RF_;
            int r0c = min(max(r0, 0), H_ - RF_);
            int4 dN = make_int4(0, 0, 0, 0), dG = dN;
            int* np = (int*)&dN;
            int* gp = (int*)&dG;
#pragma unroll
            for (int j = 0; j < GANG; ++j) {
                int bj = rf[idx[j] * 256];
                int c0 = (bj - v0 * PW) - RF_;
                int c0c = min(max(c0, 0), W_ - RF_);
                int g = (c0c >> 2) | (((c0c - c0 + 8) >> 2) << 7);
                np[j >> 1] |= idx[j] << (16 * (j & 1));
                gp[j >> 1] |= g << (16 * (j & 1));
            }
            int slot = atomicAdd(cnt, 1);
            tasks[slot * 3 + 0] = dN;
            tasks[slot * 3 + 1] = dG;
            tasks[slot * 3 + 2] = make_int4(r0c, r0c - r0, 0, 0);
        };
        for (int i = tid - 512; i < ngang; i += 512) {
            int n0 = i * GANG;
            int cn = min(GANG, N - n0);
            int vfirst = rf[n0 * 256] / PW;
            int split = cn;
            for (int j = 1; j < cn; ++j) {
                if (rf[(n0 + j) * 256] / PW != vfirst) { split = j; break; }
            }
            emit(n0, 0, split);
            if (split < cn) emit(n0, split, cn);
        }
    }
    __syncthreads();

    float best = -1.0f;
    int k0 = 0;
    for (int k = 0; k < K_; ++k) {
        float v = ss[k];
        if (v > best) { best = v; k0 = k; }
    }
    if (wv < 8) {
        for (int k = wv; k < K_; k += 8) {
            float d = 0.0f;
#pragma unroll
            for (int j = 0; j < 4; ++j)
                d = fmaf(w[k * 256 + l + j * 64], w[k0 * 256 + l + j * 64], d);
            d = allred64(d);
            if (l == 0) temporal[k] = d / best;
        }
    }
    for (int i = tid; i < LDSW_W; i += 1024) {
        int rr = i / WPR - 8;
        int cc = i % WPR - 8;
        bool ok = (rr >= 0) & (rr < RF_) & (cc >= 0) & (cc < RF_);
        spat_pad[i] = ok ? w[k0 * 256 + rr * RF_ + cc] : 0.0f;
    }
}

// ---------------------------------------------------------------------------
// Stage 1 (GANG=8 gather): one wave = one 8-neuron gang x ~12 frames.
// Lane (r = lane>>2, q = lane&3) issues 8 float4 loads, one per neuron
// window (32B pitch); the union spans 5.25 lines/row for 8 neurons -> 1.71x
// fewer L1 line-fills than pair-gather, with per-neuron request count
// unchanged. Weights: 8 float4 from the zero-padded table (shifted per
// neuron -> exact zero-pad semantics), loaded once per task. Per frame:
// 8 loads + 32 FMA + multired8 -> lane 8j stores y[n_j][t].
// ---------------------------------------------------------------------------
__global__ __launch_bounds__(256) void stage1_kernel(
    const float* __restrict__ x, const int4* __restrict__ tasks,
    const int* __restrict__ cnt, const float* __restrict__ spat_pad,
    float* __restrict__ y)
{
    int lane = threadIdx.x & 63;
    int wid  = threadIdx.x >> 6;

    int b   = blockIdx.x;
    int xcd = b & (NXCD - 1);
    int q4  = (b >> 3) & 3;
    int tg  = b >> 5;

    int taskid = tg * 4 + wid;
    if (taskid >= *cnt) return;

    int4 dN = tasks[taskid * 3 + 0];
    int4 dG = tasks[taskid * 3 + 1];
    int4 dR = tasks[taskid * 3 + 2];
    int r0c = dR.x, dr = dR.y;

    int r = lane >> 2;
    int q = lane & 3;

    // unpack per-neuron geometry
    int c0c[GANG];
    int dcp[GANG];                       // dc + 8 (pixels)
    const int* gp = (const int*)&dG;
#pragma unroll
    for (int j = 0; j < GANG; ++j) {
        int g = (gp[j >> 1] >> (16 * (j & 1))) & 0xFFFF;
        c0c[j] = (g & 0x7F) << 2;
        dcp[j] = ((g >> 7) & 7) << 2;
    }

    // per-lane weights (once per task)
    float4 w4[GANG];
    int wrow = (r + dr + 8) * WPR;
#pragma unroll
    for (int j = 0; j < GANG; ++j)
        w4[j] = *reinterpret_cast<const float4*>(spat_pad + wrow + 4 * q + dcp[j]);

    // my store target (lane 8j -> neuron j)
    int myj = lane >> 3;
    const int* np = (const int*)&dN;
    int myn = (np[myj >> 1] >> (16 * (myj & 1))) & 0xFFFF;
    float* ypn = y + (size_t)myn * T_;

    int tbase = xcd * T_PER_XCD + q4 * 12 + max(0, q4 - 2);
    int tlen  = 12 + (q4 >> 1);

    int rowoff = (r0c + r) * W_ + 4 * q;
    const float* xp = x + rowoff;
    bool b8 = (lane & 8) != 0;

    for (int tt = 0; tt < tlen; ++tt) {
        const float* fp = xp + (size_t)(tbase + tt) * HW_;
        float4 v[GANG];
#pragma unroll
        for (int j = 0; j < GANG; ++j)
            v[j] = *reinterpret_cast<const float4*>(fp + c0c[j]);
        float acc[GANG];
#pragma unroll
        for (int j = 0; j < GANG; ++j) {
            float a = v[j].x * w4[j].x;
            a = fmaf(v[j].y, w4[j].y, a);
            a = fmaf(v[j].z, w4[j].z, a);
            acc[j] = fmaf(v[j].w, w4[j].w, a);
        }
        float C = multired8(acc, b8);
        if ((lane & 7) == 0) ypn[tbase + tt] = C;
    }
}

// ---------------------------------------------------------------------------
// Stage 2: out[n, t0] = ALPHA * softplus(BETA * (sum_k y[n,t0+k]*temporal[k]
//                                                 - GAMMA))
// ---------------------------------------------------------------------------
__global__ void stage2_kernel(const float* __restrict__ y,
                              const float* __restrict__ temporal,
                              float* __restrict__ out, int N)
{
    __shared__ float tw[K_];
    if (threadIdx.x < K_) tw[threadIdx.x] = temporal[threadIdx.x];
    __syncthreads();

    int n  = blockIdx.x;
    int t0 = threadIdx.x;
    if (n >= N || t0 >= NWIN) return;

    const float* yn = y + (size_t)n * T_;
    float g = 0.0f;
#pragma unroll
    for (int k = 0; k < K_; ++k)
        g = fmaf(yn[t0 + k], tw[k], g);

    float z = BETA * (g - GAMMA);
    float sp = fmaxf(z, 0.0f) + log1pf(expf(-fabsf(z)));
    out[n * NWIN + t0] = ALPHA * sp;
}

// ---------------------------------------------------------------------------
extern "C" void kernel_launch(void* const* d_in, const int* in_sizes, int n_in,
                              void* d_out, int out_size, void* d_ws, size_t ws_size,
                              hipStream_t stream)
{
    const float* x  = (const float*)d_in[0];  // (T, H, W) f32
    const float* w  = (const float*)d_in[1];  // (K*RF*RF,) f32
    const int*   rf = (const int*)d_in[2];    // (N, 256) i32

    int N = in_sizes[2] / (RF_ * RF_);

    // worst-case task count: one split per gang
    int cap = (N + GANG - 1) / GANG + 64;

    // ws layout (4B words): [0,64) temporal | [64,128) cnt |
    // [128,1280) spat_pad | [1280, 1280+12*cap) tasks (3 x int4 each) | y: N*T
    float* temporal = (float*)d_ws;
    int*   cnt      = (int*)d_ws + 64;
    float* spat_pad = (float*)d_ws + 128;
    int4*  tasks    = (int4*)((int*)d_ws + 1280);
    float* y        = (float*)d_ws + 1280 + 12 * cap;

    int TG = (cap + 3) / 4;
    prep_kernel<<<1, 1024, 0, stream>>>(w, rf, temporal, spat_pad, cnt, tasks, N);
    stage1_kernel<<<TG * 32, 256, 0, stream>>>(x, tasks, cnt, spat_pad, y);
    stage2_kernel<<<N, 384, 0, stream>>>(y, temporal, (float*)d_out, N);
}

// Round 15
// 47.578 us; speedup vs baseline: 1.4829x; 1.4829x over previous
//
#include <hip/hip_runtime.h>
#include <math.h>

constexpr int H_ = 180, W_ = 320, RF_ = 16, K_ = 20, T_ = 400;
constexpr int HW_ = H_ * W_;
constexpr int NWIN = T_ - K_ + 1;   // 381
constexpr int PW   = W_ + 2 * RF_;  // 352 (padded width used by rf_indices)
constexpr float ALPHA = 50.0f, BETA = 1.0f, GAMMA = 0.0f;
constexpr int NXCD = 8;
constexpr int T_PER_XCD = T_ / NXCD;     // 50 frames per XCD
constexpr int GANG = 8;

// ---------------------------------------------------------------------------
// VALU-pipe cross-lane primitives (proven R10/R13)
// ---------------------------------------------------------------------------
template <int CTRL>
__device__ inline float dpp_add(float v) {
    int s = __builtin_amdgcn_update_dpp(0, __float_as_int(v), CTRL, 0xF, 0xF, true);
    return v + __int_as_float(s);
}
__device__ inline float swz_xor4_add(float v) {
    return v + __int_as_float(
        __builtin_amdgcn_ds_swizzle(__float_as_int(v), 0x101F));  // lane^4
}
#if __has_builtin(__builtin_amdgcn_permlane32_swap)
__device__ inline float pl32_merge(float a, float b) {
    auto r = __builtin_amdgcn_permlane32_swap(
        __float_as_uint(a), __float_as_uint(b), false, false);
    return __uint_as_float(r[0]) + __uint_as_float(r[1]);
}
#else
__device__ inline float pl32_merge(float a, float b) {
    bool hi = (threadIdx.x & 32) != 0;
    float keep = hi ? b : a, send = hi ? a : b;
    return keep + __shfl_xor(send, 32, 64);
}
#endif
#if __has_builtin(__builtin_amdgcn_permlane16_swap)
__device__ inline float pl16_merge(float a, float b) {
    auto r = __builtin_amdgcn_permlane16_swap(
        __float_as_uint(a), __float_as_uint(b), false, false);
    return __uint_as_float(r[0]) + __uint_as_float(r[1]);
}
#else
__device__ inline float pl16_merge(float a, float b) {
    bool hi = (threadIdx.x & 16) != 0;
    float keep = hi ? b : a, send = hi ? a : b;
    return keep + __shfl_xor(send, 16, 64);
}
#endif
__device__ inline float allred64(float v) {
    v = dpp_add<0xB1>(v);    // xor 1
    v = dpp_add<0x4E>(v);    // xor 2
    v = swz_xor4_add(v);     // xor 4
    v = dpp_add<0x128>(v);   // xor 8 (row_ror:8)
    v = pl16_merge(v, v);    // xor 16
    v = pl32_merge(v, v);    // xor 32
    return v;
}
// 8-value multi-reduce: lane 8j ends holding the full wave-sum of acc[j].
__device__ inline float multired8(const float* acc, bool b8) {
    float m0 = pl32_merge(acc[0], acc[4]);
    float m1 = pl32_merge(acc[1], acc[5]);
    float m2 = pl32_merge(acc[2], acc[6]);
    float m3 = pl32_merge(acc[3], acc[7]);
    float n0 = pl16_merge(m0, m2);
    float n1 = pl16_merge(m1, m3);
    float c0v = dpp_add<0x128>(n0);
    float c1v = dpp_add<0x128>(n1);
    float C = b8 ? c1v : c0v;
    C = dpp_add<0xB1>(C);
    C = dpp_add<0x4E>(C);
    C = swz_xor4_add(C);
    return C;
}

// ---------------------------------------------------------------------------
// prep: factorize w (K x 256, exact rank-1) into spatial[256] + temporal[K].
// 8 waves; DPP allreduce per row; argmax pivot; LS projection.
// ---------------------------------------------------------------------------
__global__ __launch_bounds__(512) void prep_kernel(
    const float* __restrict__ w,
    float* __restrict__ spatial, float* __restrict__ temporal)
{
    __shared__ float ss[32];
    int tid = threadIdx.x, wv = tid >> 6, l = tid & 63;

    for (int k = wv; k < K_; k += 8) {
        float s = 0.0f;
#pragma unroll
        for (int j = 0; j < 4; ++j) {
            float v = w[k * 256 + l + j * 64];
            s = fmaf(v, v, s);
        }
        s = allred64(s);
        if (l == 0) ss[k] = s;
    }
    __syncthreads();

    float best = -1.0f;
    int k0 = 0;
    for (int k = 0; k < K_; ++k) {
        float v = ss[k];
        if (v > best) { best = v; k0 = k; }
    }

    for (int k = wv; k < K_; k += 8) {
        float d = 0.0f;
#pragma unroll
        for (int j = 0; j < 4; ++j)
            d = fmaf(w[k * 256 + l + j * 64], w[k0 * 256 + l + j * 64], d);
        d = allred64(d);
        if (l == 0) temporal[k] = d / best;
    }
    if (tid < 256) spatial[tid] = w[k0 * 256 + tid];
}

// ---------------------------------------------------------------------------
// Stage 1 (gang-of-8, self-describing): one wave = neurons 8g..8g+7 over a
// 12/13-frame t-slice. All geometry derived inline from rf in fully-static
// unrolled loops (NO runtime-indexed arrays -> no scratch; R14's failure).
// Lane (r = lane>>2, q = lane&3) issues 8 float4 window loads per frame,
// batched 2 frames (16 loads in flight); mosaic neighbors at 32B pitch
// share L1 lines (~84 lines per gang-frame vs 144 for 8 singles).
// Weights: guarded float4 from spatial (col shifts are multiples of 4 on
// the mosaic lattice -> whole-quad in/out, exact zero-pad semantics).
// Two multired8 per chunk; lane 8j stores y[gang_j][t] and [t+1].
// ---------------------------------------------------------------------------
__global__ __launch_bounds__(256) void stage1_kernel(
    const float* __restrict__ x, const int* __restrict__ rf,
    const float* __restrict__ spatial, float* __restrict__ y, int N)
{
    int lane = threadIdx.x & 63;
    int wid  = threadIdx.x >> 6;

    int b   = blockIdx.x;
    int xcd = b & (NXCD - 1);
    int q4  = (b >> 3) & 3;
    int tg  = b >> 5;

    int NG = (N + GANG - 1) / GANG;
    int gi = tg * 4 + wid;
    if (gi >= NG) return;
    int gb = gi * GANG;

    int r = lane >> 2;
    int q = lane & 3;

    // --- per-neuron geometry + weights, fully static ---
    int   off[GANG];
    float4 w4[GANG];
#pragma unroll
    for (int j = 0; j < GANG; ++j) {
        int nj   = min(gb + j, N - 1);
        int base = rf[nj * 256];
        int v0   = base / PW;
        int r0   = v0 - RF_;
        int c0   = (base - v0 * PW) - RF_;
        int r0c  = min(max(r0, 0), H_ - RF_);
        int c0c  = min(max(c0, 0), W_ - RF_);
        off[j] = (r0c + r) * W_ + c0c + 4 * q;
        int rr = r + (r0c - r0);
        int cc = 4 * q + (c0c - c0);           // multiple of 4
        bool ok = (rr >= 0) & (rr < RF_) & (cc >= 0) & (cc < RF_);
        float4 wz = make_float4(0.f, 0.f, 0.f, 0.f);
        if (ok) wz = *reinterpret_cast<const float4*>(spatial + rr * RF_ + cc);
        w4[j] = wz;
    }

    // store target: lane 8j -> neuron gb+j (pure arithmetic, no array)
    float* ypn = y + (size_t)min(gb + (lane >> 3), N - 1) * T_;
    bool b8 = (lane & 8) != 0;

    // t-slice: {0,12,24,37} + len {12,12,13,13} within this XCD's 50 frames
    int tbase = xcd * T_PER_XCD + q4 * 12 + max(0, q4 - 2);
    int tend  = tbase + 12 + (q4 >> 1);

    for (int t = tbase; t < tend; t += 2) {
        int t2 = min(t + 1, T_ - 1);            // safe load for odd tail
        const float* fA = x + (size_t)t  * HW_;
        const float* fB = x + (size_t)t2 * HW_;
        float4 vA[GANG], vB[GANG];
#pragma unroll
        for (int j = 0; j < GANG; ++j)
            vA[j] = *reinterpret_cast<const float4*>(fA + off[j]);
#pragma unroll
        for (int j = 0; j < GANG; ++j)
            vB[j] = *reinterpret_cast<const float4*>(fB + off[j]);

        float aA[GANG], aB[GANG];
#pragma unroll
        for (int j = 0; j < GANG; ++j) {
            float u = vA[j].x * w4[j].x;
            u = fmaf(vA[j].y, w4[j].y, u);
            u = fmaf(vA[j].z, w4[j].z, u);
            aA[j] = fmaf(vA[j].w, w4[j].w, u);
            float v = vB[j].x * w4[j].x;
            v = fmaf(vB[j].y, w4[j].y, v);
            v = fmaf(vB[j].z, w4[j].z, v);
            aB[j] = fmaf(vB[j].w, w4[j].w, v);
        }
        float CA = multired8(aA, b8);
        float CB = multired8(aB, b8);
        if ((lane & 7) == 0) {
            ypn[t] = CA;
            if (t + 1 < tend) ypn[t + 1] = CB;
        }
    }
}

// ---------------------------------------------------------------------------
// Stage 2: out[n, t0] = ALPHA * softplus(BETA * (sum_k y[n,t0+k]*temporal[k]
//                                                 - GAMMA))
// ---------------------------------------------------------------------------
__global__ void stage2_kernel(const float* __restrict__ y,
                              const float* __restrict__ temporal,
                              float* __restrict__ out, int N)
{
    __shared__ float tw[K_];
    if (threadIdx.x < K_) tw[threadIdx.x] = temporal[threadIdx.x];
    __syncthreads();

    int n  = blockIdx.x;
    int t0 = threadIdx.x;
    if (n >= N || t0 >= NWIN) return;

    const float* yn = y + (size_t)n * T_;
    float g = 0.0f;
#pragma unroll
    for (int k = 0; k < K_; ++k)
        g = fmaf(yn[t0 + k], tw[k], g);

    float z = BETA * (g - GAMMA);
    float sp = fmaxf(z, 0.0f) + log1pf(expf(-fabsf(z)));
    out[n * NWIN + t0] = ALPHA * sp;
}

// ---------------------------------------------------------------------------
extern "C" void kernel_launch(void* const* d_in, const int* in_sizes, int n_in,
                              void* d_out, int out_size, void* d_ws, size_t ws_size,
                              hipStream_t stream)
{
    const float* x  = (const float*)d_in[0];  // (T, H, W) f32
    const float* w  = (const float*)d_in[1];  // (K*RF*RF,) f32
    const int*   rf = (const int*)d_in[2];    // (N, 256) i32

    int N = in_sizes[2] / (RF_ * RF_);

    // ws layout (4B words): [0,256) spatial | [256,320) temporal | y : N*T
    float* spatial  = (float*)d_ws;
    float* temporal = spatial + 256;
    float* y        = spatial + 320;

    int NG = (N + GANG - 1) / GANG;
    int blocks = (NG + 3) / 4 * 32;           // x 8 XCD x 4 t-slices

    prep_kernel<<<1, 512, 0, stream>>>(w, spatial, temporal);
    stage1_kernel<<<blocks, 256, 0, stream>>>(x, rf, spatial, y, N);
    stage2_kernel<<<N, 384, 0, stream>>>(y, temporal, (float*)d_out, N);
}

// Round 16
// 46.566 us; speedup vs baseline: 1.5151x; 1.0217x over previous
//
#include <hip/hip_runtime.h>
#include <math.h>

constexpr int H_ = 180, W_ = 320, RF_ = 16, K_ = 20, T_ = 400;
constexpr int HW_ = H_ * W_;
constexpr int NWIN = T_ - K_ + 1;   // 381
constexpr int PW   = W_ + 2 * RF_;  // 352 (padded width used by rf_indices)
constexpr float ALPHA = 50.0f, BETA = 1.0f, GAMMA = 0.0f;
constexpr int NXCD = 8;
constexpr int T_PER_XCD = T_ / NXCD;     // 50 frames per XCD
constexpr int T_HALF = T_PER_XCD / 2;    // 25 frames per wave
constexpr int GANG = 4;

// ---------------------------------------------------------------------------
// VALU-pipe cross-lane primitives (proven R10/R13)
// ---------------------------------------------------------------------------
template <int CTRL>
__device__ inline float dpp_add(float v) {
    int s = __builtin_amdgcn_update_dpp(0, __float_as_int(v), CTRL, 0xF, 0xF, true);
    return v + __int_as_float(s);
}
__device__ inline float swz_xor4_add(float v) {
    return v + __int_as_float(
        __builtin_amdgcn_ds_swizzle(__float_as_int(v), 0x101F));  // lane^4
}
#if __has_builtin(__builtin_amdgcn_permlane32_swap)
__device__ inline float pl32_merge(float a, float b) {
    auto r = __builtin_amdgcn_permlane32_swap(
        __float_as_uint(a), __float_as_uint(b), false, false);
    return __uint_as_float(r[0]) + __uint_as_float(r[1]);
}
#else
__device__ inline float pl32_merge(float a, float b) {
    bool hi = (threadIdx.x & 32) != 0;
    float keep = hi ? b : a, send = hi ? a : b;
    return keep + __shfl_xor(send, 32, 64);
}
#endif
#if __has_builtin(__builtin_amdgcn_permlane16_swap)
__device__ inline float pl16_merge(float a, float b) {
    auto r = __builtin_amdgcn_permlane16_swap(
        __float_as_uint(a), __float_as_uint(b), false, false);
    return __uint_as_float(r[0]) + __uint_as_float(r[1]);
}
#else
__device__ inline float pl16_merge(float a, float b) {
    bool hi = (threadIdx.x & 16) != 0;
    float keep = hi ? b : a, send = hi ? a : b;
    return keep + __shfl_xor(send, 16, 64);
}
#endif
__device__ inline float allred64(float v) {
    v = dpp_add<0xB1>(v);    // xor 1
    v = dpp_add<0x4E>(v);    // xor 2
    v = swz_xor4_add(v);     // xor 4
    v = dpp_add<0x128>(v);   // xor 8 (row_ror:8)
    v = pl16_merge(v, v);    // xor 16
    v = pl32_merge(v, v);    // xor 32
    return v;
}
// 8-value multi-reduce: lane 8j ends holding the full wave-sum of acc[j].
__device__ inline float multired8(const float* acc, bool b8) {
    float m0 = pl32_merge(acc[0], acc[4]);
    float m1 = pl32_merge(acc[1], acc[5]);
    float m2 = pl32_merge(acc[2], acc[6]);
    float m3 = pl32_merge(acc[3], acc[7]);
    float n0 = pl16_merge(m0, m2);
    float n1 = pl16_merge(m1, m3);
    float c0v = dpp_add<0x128>(n0);
    float c1v = dpp_add<0x128>(n1);
    float C = b8 ? c1v : c0v;
    C = dpp_add<0xB1>(C);
    C = dpp_add<0x4E>(C);
    C = swz_xor4_add(C);
    return C;
}

// ---------------------------------------------------------------------------
// prep: waves 0-7 factorize w (exact rank-1) -> spatial[256] + temporal[K];
// waves 8-15 build QUAD tasks: neurons 4i..4i+3 split into runs of equal
// padded row v0 (line-sharing requires same row; correctness does not),
// each run padded to 4 slots by repeating its last neuron.
// Task = int4 { n0|n1<<16, n2|n3<<16, 0, 0 } — geometry re-derived in stage1.
// ---------------------------------------------------------------------------
__global__ __launch_bounds__(1024) void prep_kernel(
    const float* __restrict__ w, const int* __restrict__ rf,
    float* __restrict__ spatial, float* __restrict__ temporal,
    int* __restrict__ cnt, int4* __restrict__ tasks, int N)
{
    __shared__ float ss[32];
    int tid = threadIdx.x, wv = tid >> 6, l = tid & 63;
    if (tid == 0) *cnt = 0;
    __syncthreads();

    if (wv < 8) {
        for (int k = wv; k < K_; k += 8) {
            float s = 0.0f;
#pragma unroll
            for (int j = 0; j < 4; ++j) {
                float v = w[k * 256 + l + j * 64];
                s = fmaf(v, v, s);
            }
            s = allred64(s);
            if (l == 0) ss[k] = s;
        }
    } else {
        int nquad = (N + GANG - 1) / GANG;
        for (int i = tid - 512; i < nquad; i += 512) {
            int n0 = i * GANG;
            int cn = min(GANG, N - n0);
            int s = 0;
            while (s < cn) {
                int v = rf[(n0 + s) * 256] / PW;
                int e = s + 1;
                while (e < cn && rf[(n0 + e) * 256] / PW == v) ++e;
                int id0 = n0 + s;
                int id1 = n0 + min(s + 1, e - 1);
                int id2 = n0 + min(s + 2, e - 1);
                int id3 = n0 + min(s + 3, e - 1);
                int slot = atomicAdd(cnt, 1);
                tasks[slot] = make_int4(id0 | (id1 << 16), id2 | (id3 << 16), 0, 0);
                s = e;
            }
        }
    }
    __syncthreads();

    float best = -1.0f;
    int k0 = 0;
    for (int k = 0; k < K_; ++k) {
        float v = ss[k];
        if (v > best) { best = v; k0 = k; }
    }
    if (wv < 8) {
        for (int k = wv; k < K_; k += 8) {
            float d = 0.0f;
#pragma unroll
            for (int j = 0; j < 4; ++j)
                d = fmaf(w[k * 256 + l + j * 64], w[k0 * 256 + l + j * 64], d);
            d = allred64(d);
            if (l == 0) temporal[k] = d / best;
        }
    }
    if (tid < 256) spatial[tid] = w[k0 * 256 + tid];
}

// ---------------------------------------------------------------------------
// Stage 1 (quad-gather): one wave = one 4-neuron task x 25 frames.
// R13's proven skeleton with windows 2 -> 4. Chunk = 2 frames x 4 windows =
// 8 float4 loads in flight (same as R13), 32 FMA, ONE multired8
// (acc[f*4+w]); lane 8j stores y[n_w][t+f]. Same-row windows at 32B pitch:
// union span 160B -> ~2.9 lines/row per 4 neurons vs 2x2.25 for two pairs
// (1.55x fewer L1 line-fills). Geometry from rf in fully-static unrolls;
// store-target id via branchless selects (no runtime-indexed arrays).
// ---------------------------------------------------------------------------
__global__ __launch_bounds__(256) void stage1_kernel(
    const float* __restrict__ x, const int* __restrict__ rf,
    const int4* __restrict__ tasks, const int* __restrict__ cnt,
    const float* __restrict__ spatial, float* __restrict__ y)
{
    int lane = threadIdx.x & 63;
    int wid  = threadIdx.x >> 6;

    int b    = blockIdx.x;
    int xcd  = b & (NXCD - 1);
    int half = (b >> 3) & 1;
    int tg   = b >> 4;

    int taskid = tg * 4 + wid;
    if (taskid >= *cnt) return;

    int4 d = tasks[taskid];
    int t0 = xcd * T_PER_XCD + half * T_HALF;

    int r = lane >> 2;
    int q = lane & 3;

    // --- geometry + weights, fully static (ids extracted inline) ---
    int    off[GANG];
    float4 w4[GANG];
#pragma unroll
    for (int j = 0; j < GANG; ++j) {
        int pair = (j & 2) ? d.y : d.x;
        int nj   = (j & 1) ? (pair >> 16) & 0xFFFF : pair & 0xFFFF;
        int base = rf[nj * 256];
        int v0   = base / PW;
        int r0   = v0 - RF_;
        int c0   = (base - v0 * PW) - RF_;
        int r0c  = min(max(r0, 0), H_ - RF_);
        int c0c  = min(max(c0, 0), W_ - RF_);
        off[j] = (r0c + r) * W_ + c0c + 4 * q;
        int rr = r + (r0c - r0);
        int cc = 4 * q + (c0c - c0);           // multiple of 4 on the lattice
        bool ok = (rr >= 0) & (rr < RF_) & (cc >= 0) & (cc < RF_);
        float4 wz = make_float4(0.f, 0.f, 0.f, 0.f);
        if (ok) wz = *reinterpret_cast<const float4*>(spatial + rr * RF_ + cc);
        w4[j] = wz;
    }

    // store target: lane 8j -> (w = j&3, f = j>>2); id via branchless selects
    int jmy = lane >> 3;
    int psel = (jmy & 2) ? d.y : d.x;
    int nmy  = (jmy & 1) ? (psel >> 16) & 0xFFFF : psel & 0xFFFF;
    int fmy  = jmy >> 2;
    float* ypn = y + (size_t)nmy * T_;
    bool b8 = (lane & 8) != 0;

    const float* xt = x + (size_t)t0 * HW_;

    // 12 chunks of 2 frames (local 0..23)
    for (int tt = 0; tt < 24; tt += 2) {
        const float* fA = xt + (size_t)tt * HW_;
        const float* fB = fA + HW_;
        float4 vA[GANG], vB[GANG];
#pragma unroll
        for (int j = 0; j < GANG; ++j)
            vA[j] = *reinterpret_cast<const float4*>(fA + off[j]);
#pragma unroll
        for (int j = 0; j < GANG; ++j)
            vB[j] = *reinterpret_cast<const float4*>(fB + off[j]);

        float acc[2 * GANG];
#pragma unroll
        for (int j = 0; j < GANG; ++j) {
            float u = vA[j].x * w4[j].x;
            u = fmaf(vA[j].y, w4[j].y, u);
            u = fmaf(vA[j].z, w4[j].z, u);
            acc[j] = fmaf(vA[j].w, w4[j].w, u);
            float v = vB[j].x * w4[j].x;
            v = fmaf(vB[j].y, w4[j].y, v);
            v = fmaf(vB[j].z, w4[j].z, v);
            acc[GANG + j] = fmaf(vB[j].w, w4[j].w, v);
        }
        float C = multired8(acc, b8);
        if ((lane & 7) == 0) ypn[t0 + tt + fmy] = C;
    }

    // tail frame (local 24)
    {
        const float* fA = xt + (size_t)24 * HW_;
        float acc[2 * GANG];
#pragma unroll
        for (int j = 0; j < GANG; ++j) {
            float4 v = *reinterpret_cast<const float4*>(fA + off[j]);
            float u = v.x * w4[j].x;
            u = fmaf(v.y, w4[j].y, u);
            u = fmaf(v.z, w4[j].z, u);
            acc[j] = fmaf(v.w, w4[j].w, u);
            acc[GANG + j] = 0.0f;
        }
        float C = multired8(acc, b8);
        if (((lane & 7) == 0) && fmy == 0) ypn[t0 + 24] = C;
    }
}

// ---------------------------------------------------------------------------
// Stage 2: out[n, t0] = ALPHA * softplus(BETA * (sum_k y[n,t0+k]*temporal[k]
//                                                 - GAMMA))
// ---------------------------------------------------------------------------
__global__ void stage2_kernel(const float* __restrict__ y,
                              const float* __restrict__ temporal,
                              float* __restrict__ out, int N)
{
    __shared__ float tw[K_];
    if (threadIdx.x < K_) tw[threadIdx.x] = temporal[threadIdx.x];
    __syncthreads();

    int n  = blockIdx.x;
    int t0 = threadIdx.x;
    if (n >= N || t0 >= NWIN) return;

    const float* yn = y + (size_t)n * T_;
    float g = 0.0f;
#pragma unroll
    for (int k = 0; k < K_; ++k)
        g = fmaf(yn[t0 + k], tw[k], g);

    float z = BETA * (g - GAMMA);
    float sp = fmaxf(z, 0.0f) + log1pf(expf(-fabsf(z)));
    out[n * NWIN + t0] = ALPHA * sp;
}

// ---------------------------------------------------------------------------
extern "C" void kernel_launch(void* const* d_in, const int* in_sizes, int n_in,
                              void* d_out, int out_size, void* d_ws, size_t ws_size,
                              hipStream_t stream)
{
    const float* x  = (const float*)d_in[0];  // (T, H, W) f32
    const float* w  = (const float*)d_in[1];  // (K*RF*RF,) f32
    const int*   rf = (const int*)d_in[2];    // (N, 256) i32

    int N = in_sizes[2] / (RF_ * RF_);

    // ws layout (4B words): [0,256) spatial | [256,320) temporal |
    // [320,384) cnt | [384, 384+4N) tasks (int4, cap N) | y : N*T
    float* spatial  = (float*)d_ws;
    float* temporal = spatial + 256;
    int*   cnt      = (int*)d_ws + 320;
    int4*  tasks    = (int4*)((int*)d_ws + 384);
    float* y        = (float*)d_ws + 384 + 4 * N;

    // grid sized for worst case (cnt <= N); excess waves exit on *cnt.
    int TG = (N + 3) / 4;
    prep_kernel<<<1, 1024, 0, stream>>>(w, rf, spatial, temporal, cnt, tasks, N);
    stage1_kernel<<<TG * 16, 256, 0, stream>>>(x, rf, tasks, cnt, spatial, y);
    stage2_kernel<<<N, 384, 0, stream>>>(y, temporal, (float*)d_out, N);
}

// Round 17
// 45.658 us; speedup vs baseline: 1.5452x; 1.0199x over previous
//
#include <hip/hip_runtime.h>
#include <math.h>

constexpr int H_ = 180, W_ = 320, RF_ = 16, K_ = 20, T_ = 400;
constexpr int HW_ = H_ * W_;
constexpr int NWIN = T_ - K_ + 1;   // 381
constexpr int PW   = W_ + 2 * RF_;  // 352 (padded width used by rf_indices)
constexpr float ALPHA = 50.0f, BETA = 1.0f, GAMMA = 0.0f;
constexpr int NXCD = 8;
constexpr int T_PER_XCD = T_ / NXCD;     // 50 frames per XCD
constexpr int T_HALF = T_PER_XCD / 2;    // 25 frames per wave
constexpr int GANG = 4;

// ---------------------------------------------------------------------------
// VALU-pipe cross-lane primitives (proven R10/R13)
// ---------------------------------------------------------------------------
template <int CTRL>
__device__ inline float dpp_add(float v) {
    int s = __builtin_amdgcn_update_dpp(0, __float_as_int(v), CTRL, 0xF, 0xF, true);
    return v + __int_as_float(s);
}
__device__ inline float swz_xor4_add(float v) {
    return v + __int_as_float(
        __builtin_amdgcn_ds_swizzle(__float_as_int(v), 0x101F));  // lane^4
}
#if __has_builtin(__builtin_amdgcn_permlane32_swap)
__device__ inline float pl32_merge(float a, float b) {
    auto r = __builtin_amdgcn_permlane32_swap(
        __float_as_uint(a), __float_as_uint(b), false, false);
    return __uint_as_float(r[0]) + __uint_as_float(r[1]);
}
#else
__device__ inline float pl32_merge(float a, float b) {
    bool hi = (threadIdx.x & 32) != 0;
    float keep = hi ? b : a, send = hi ? a : b;
    return keep + __shfl_xor(send, 32, 64);
}
#endif
#if __has_builtin(__builtin_amdgcn_permlane16_swap)
__device__ inline float pl16_merge(float a, float b) {
    auto r = __builtin_amdgcn_permlane16_swap(
        __float_as_uint(a), __float_as_uint(b), false, false);
    return __uint_as_float(r[0]) + __uint_as_float(r[1]);
}
#else
__device__ inline float pl16_merge(float a, float b) {
    bool hi = (threadIdx.x & 16) != 0;
    float keep = hi ? b : a, send = hi ? a : b;
    return keep + __shfl_xor(send, 16, 64);
}
#endif
__device__ inline float allred64(float v) {
    v = dpp_add<0xB1>(v);    // xor 1
    v = dpp_add<0x4E>(v);    // xor 2
    v = swz_xor4_add(v);     // xor 4
    v = dpp_add<0x128>(v);   // xor 8 (row_ror:8)
    v = pl16_merge(v, v);    // xor 16
    v = pl32_merge(v, v);    // xor 32
    return v;
}
// 8-value multi-reduce: lane 8j ends holding the full wave-sum of acc[j].
__device__ inline float multired8(const float* acc, bool b8) {
    float m0 = pl32_merge(acc[0], acc[4]);
    float m1 = pl32_merge(acc[1], acc[5]);
    float m2 = pl32_merge(acc[2], acc[6]);
    float m3 = pl32_merge(acc[3], acc[7]);
    float n0 = pl16_merge(m0, m2);
    float n1 = pl16_merge(m1, m3);
    float c0v = dpp_add<0x128>(n0);
    float c1v = dpp_add<0x128>(n1);
    float C = b8 ? c1v : c0v;
    C = dpp_add<0xB1>(C);
    C = dpp_add<0x4E>(C);
    C = swz_xor4_add(C);
    return C;
}

// ---------------------------------------------------------------------------
// prep: waves 0-7 factorize w (exact rank-1) -> spatial[256] + temporal[K];
// waves 8-15 build QUAD tasks: neurons 4i..4i+3 split into runs of equal
// padded row v0 (line-sharing requires same row; correctness does not),
// each run padded to 4 slots by repeating its last neuron.
// Task = int4 { n0|n1<<16, n2|n3<<16, 0, 0 } — geometry re-derived in stage1.
// ---------------------------------------------------------------------------
__global__ __launch_bounds__(1024) void prep_kernel(
    const float* __restrict__ w, const int* __restrict__ rf,
    float* __restrict__ spatial, float* __restrict__ temporal,
    int* __restrict__ cnt, int4* __restrict__ tasks, int N)
{
    __shared__ float ss[32];
    int tid = threadIdx.x, wv = tid >> 6, l = tid & 63;
    if (tid == 0) *cnt = 0;
    __syncthreads();

    if (wv < 8) {
        for (int k = wv; k < K_; k += 8) {
            float s = 0.0f;
#pragma unroll
            for (int j = 0; j < 4; ++j) {
                float v = w[k * 256 + l + j * 64];
                s = fmaf(v, v, s);
            }
            s = allred64(s);
            if (l == 0) ss[k] = s;
        }
    } else {
        int nquad = (N + GANG - 1) / GANG;
        for (int i = tid - 512; i < nquad; i += 512) {
            int n0 = i * GANG;
            int cn = min(GANG, N - n0);
            int s = 0;
            while (s < cn) {
                int v = rf[(n0 + s) * 256] / PW;
                int e = s + 1;
                while (e < cn && rf[(n0 + e) * 256] / PW == v) ++e;
                int id0 = n0 + s;
                int id1 = n0 + min(s + 1, e - 1);
                int id2 = n0 + min(s + 2, e - 1);
                int id3 = n0 + min(s + 3, e - 1);
                int slot = atomicAdd(cnt, 1);
                tasks[slot] = make_int4(id0 | (id1 << 16), id2 | (id3 << 16), 0, 0);
                s = e;
            }
        }
    }
    __syncthreads();

    float best = -1.0f;
    int k0 = 0;
    for (int k = 0; k < K_; ++k) {
        float v = ss[k];
        if (v > best) { best = v; k0 = k; }
    }
    if (wv < 8) {
        for (int k = wv; k < K_; k += 8) {
            float d = 0.0f;
#pragma unroll
            for (int j = 0; j < 4; ++j)
                d = fmaf(w[k * 256 + l + j * 64], w[k0 * 256 + l + j * 64], d);
            d = allred64(d);
            if (l == 0) temporal[k] = d / best;
        }
    }
    if (tid < 256) spatial[tid] = w[k0 * 256 + tid];
}

// ---------------------------------------------------------------------------
// Stage 1 (quad-gather): one wave = one 4-neuron task x 25 frames.
// R13's proven skeleton with windows 2 -> 4. Chunk = 2 frames x 4 windows =
// 8 float4 loads in flight (same as R13), 32 FMA, ONE multired8
// (acc[f*4+w]); lane 8j stores y[n_w][t+f]. Same-row windows at 32B pitch:
// union span 160B -> ~2.9 lines/row per 4 neurons vs 2x2.25 for two pairs
// (1.55x fewer L1 line-fills). Geometry from rf in fully-static unrolls;
// store-target id via branchless selects (no runtime-indexed arrays).
// ---------------------------------------------------------------------------
__global__ __launch_bounds__(256) void stage1_kernel(
    const float* __restrict__ x, const int* __restrict__ rf,
    const int4* __restrict__ tasks, const int* __restrict__ cnt,
    const float* __restrict__ spatial, float* __restrict__ y)
{
    int lane = threadIdx.x & 63;
    int wid  = threadIdx.x >> 6;

    int b    = blockIdx.x;
    int xcd  = b & (NXCD - 1);
    int half = (b >> 3) & 1;
    int tg   = b >> 4;

    int taskid = tg * 4 + wid;
    if (taskid >= *cnt) return;

    int4 d = tasks[taskid];
    int t0 = xcd * T_PER_XCD + half * T_HALF;

    int r = lane >> 2;
    int q = lane & 3;

    // --- geometry + weights, fully static (ids extracted inline) ---
    int    off[GANG];
    float4 w4[GANG];
#pragma unroll
    for (int j = 0; j < GANG; ++j) {
        int pair = (j & 2) ? d.y : d.x;
        int nj   = (j & 1) ? (pair >> 16) & 0xFFFF : pair & 0xFFFF;
        int base = rf[nj * 256];
        int v0   = base / PW;
        int r0   = v0 - RF_;
        int c0   = (base - v0 * PW) - RF_;
        int r0c  = min(max(r0, 0), H_ - RF_);
        int c0c  = min(max(c0, 0), W_ - RF_);
        off[j] = (r0c + r) * W_ + c0c + 4 * q;
        int rr = r + (r0c - r0);
        int cc = 4 * q + (c0c - c0);           // multiple of 4 on the lattice
        bool ok = (rr >= 0) & (rr < RF_) & (cc >= 0) & (cc < RF_);
        float4 wz = make_float4(0.f, 0.f, 0.f, 0.f);
        if (ok) wz = *reinterpret_cast<const float4*>(spatial + rr * RF_ + cc);
        w4[j] = wz;
    }

    // store target: lane 8j -> (w = j&3, f = j>>2); id via branchless selects
    int jmy = lane >> 3;
    int psel = (jmy & 2) ? d.y : d.x;
    int nmy  = (jmy & 1) ? (psel >> 16) & 0xFFFF : psel & 0xFFFF;
    int fmy  = jmy >> 2;
    float* ypn = y + (size_t)nmy * T_;
    bool b8 = (lane & 8) != 0;

    const float* xt = x + (size_t)t0 * HW_;

    // 12 chunks of 2 frames (local 0..23)
    for (int tt = 0; tt < 24; tt += 2) {
        const float* fA = xt + (size_t)tt * HW_;
        const float* fB = fA + HW_;
        float4 vA[GANG], vB[GANG];
#pragma unroll
        for (int j = 0; j < GANG; ++j)
            vA[j] = *reinterpret_cast<const float4*>(fA + off[j]);
#pragma unroll
        for (int j = 0; j < GANG; ++j)
            vB[j] = *reinterpret_cast<const float4*>(fB + off[j]);

        float acc[2 * GANG];
#pragma unroll
        for (int j = 0; j < GANG; ++j) {
            float u = vA[j].x * w4[j].x;
            u = fmaf(vA[j].y, w4[j].y, u);
            u = fmaf(vA[j].z, w4[j].z, u);
            acc[j] = fmaf(vA[j].w, w4[j].w, u);
            float v = vB[j].x * w4[j].x;
            v = fmaf(vB[j].y, w4[j].y, v);
            v = fmaf(vB[j].z, w4[j].z, v);
            acc[GANG + j] = fmaf(vB[j].w, w4[j].w, v);
        }
        float C = multired8(acc, b8);
        if ((lane & 7) == 0) ypn[t0 + tt + fmy] = C;
    }

    // tail frame (local 24)
    {
        const float* fA = xt + (size_t)24 * HW_;
        float acc[2 * GANG];
#pragma unroll
        for (int j = 0; j < GANG; ++j) {
            float4 v = *reinterpret_cast<const float4*>(fA + off[j]);
            float u = v.x * w4[j].x;
            u = fmaf(v.y, w4[j].y, u);
            u = fmaf(v.z, w4[j].z, u);
            acc[j] = fmaf(v.w, w4[j].w, u);
            acc[GANG + j] = 0.0f;
        }
        float C = multired8(acc, b8);
        if (((lane & 7) == 0) && fmy == 0) ypn[t0 + 24] = C;
    }
}

// ---------------------------------------------------------------------------
// Stage 2: out[n, t0] = ALPHA * softplus(BETA * (sum_k y[n,t0+k]*temporal[k]
//                                                 - GAMMA))
// ---------------------------------------------------------------------------
__global__ void stage2_kernel(const float* __restrict__ y,
                              const float* __restrict__ temporal,
                              float* __restrict__ out, int N)
{
    __shared__ float tw[K_];
    if (threadIdx.x < K_) tw[threadIdx.x] = temporal[threadIdx.x];
    __syncthreads();

    int n  = blockIdx.x;
    int t0 = threadIdx.x;
    if (n >= N || t0 >= NWIN) return;

    const float* yn = y + (size_t)n * T_;
    float g = 0.0f;
#pragma unroll
    for (int k = 0; k < K_; ++k)
        g = fmaf(yn[t0 + k], tw[k], g);

    float z = BETA * (g - GAMMA);
    float sp = fmaxf(z, 0.0f) + log1pf(expf(-fabsf(z)));
    out[n * NWIN + t0] = ALPHA * sp;
}

// ---------------------------------------------------------------------------
extern "C" void kernel_launch(void* const* d_in, const int* in_sizes, int n_in,
                              void* d_out, int out_size, void* d_ws, size_t ws_size,
                              hipStream_t stream)
{
    const float* x  = (const float*)d_in[0];  // (T, H, W) f32
    const float* w  = (const float*)d_in[1];  // (K*RF*RF,) f32
    const int*   rf = (const int*)d_in[2];    // (N, 256) i32

    int N = in_sizes[2] / (RF_ * RF_);

    // ws layout (4B words): [0,256) spatial | [256,320) temporal |
    // [320,384) cnt | [384, 384+4N) tasks (int4, cap N) | y : N*T
    float* spatial  = (float*)d_ws;
    float* temporal = spatial + 256;
    int*   cnt      = (int*)d_ws + 320;
    int4*  tasks    = (int4*)((int*)d_ws + 384);
    float* y        = (float*)d_ws + 384 + 4 * N;

    // grid sized for worst case (cnt <= N); excess waves exit on *cnt.
    int TG = (N + 3) / 4;
    prep_kernel<<<1, 1024, 0, stream>>>(w, rf, spatial, temporal, cnt, tasks, N);
    stage1_kernel<<<TG * 16, 256, 0, stream>>>(x, rf, tasks, cnt, spatial, y);
    stage2_kernel<<<N, 384, 0, stream>>>(y, temporal, (float*)d_out, N);
}

// Round 18
// 45.547 us; speedup vs baseline: 1.5490x; 1.0024x over previous
//
#include <hip/hip_runtime.h>
#include <math.h>

constexpr int H_ = 180, W_ = 320, RF_ = 16, K_ = 20, T_ = 400;
constexpr int HW_ = H_ * W_;
constexpr int NWIN = T_ - K_ + 1;   // 381
constexpr int PW   = W_ + 2 * RF_;  // 352 (padded width used by rf_indices)
constexpr float ALPHA = 50.0f, BETA = 1.0f, GAMMA = 0.0f;
constexpr int NXCD = 8;
constexpr int T_PER_XCD = T_ / NXCD;     // 50 frames per XCD
constexpr int T_HALF = T_PER_XCD / 2;    // 25 frames per wave
constexpr int GANG = 4;

// ---------------------------------------------------------------------------
// VALU-pipe cross-lane primitives (proven R10/R13)
// ---------------------------------------------------------------------------
template <int CTRL>
__device__ inline float dpp_add(float v) {
    int s = __builtin_amdgcn_update_dpp(0, __float_as_int(v), CTRL, 0xF, 0xF, true);
    return v + __int_as_float(s);
}
__device__ inline float swz_xor4_add(float v) {
    return v + __int_as_float(
        __builtin_amdgcn_ds_swizzle(__float_as_int(v), 0x101F));  // lane^4
}
#if __has_builtin(__builtin_amdgcn_permlane32_swap)
__device__ inline float pl32_merge(float a, float b) {
    auto r = __builtin_amdgcn_permlane32_swap(
        __float_as_uint(a), __float_as_uint(b), false, false);
    return __uint_as_float(r[0]) + __uint_as_float(r[1]);
}
#else
__device__ inline float pl32_merge(float a, float b) {
    bool hi = (threadIdx.x & 32) != 0;
    float keep = hi ? b : a, send = hi ? a : b;
    return keep + __shfl_xor(send, 32, 64);
}
#endif
#if __has_builtin(__builtin_amdgcn_permlane16_swap)
__device__ inline float pl16_merge(float a, float b) {
    auto r = __builtin_amdgcn_permlane16_swap(
        __float_as_uint(a), __float_as_uint(b), false, false);
    return __uint_as_float(r[0]) + __uint_as_float(r[1]);
}
#else
__device__ inline float pl16_merge(float a, float b) {
    bool hi = (threadIdx.x & 16) != 0;
    float keep = hi ? b : a, send = hi ? a : b;
    return keep + __shfl_xor(send, 16, 64);
}
#endif
__device__ inline float allred64(float v) {
    v = dpp_add<0xB1>(v);    // xor 1
    v = dpp_add<0x4E>(v);    // xor 2
    v = swz_xor4_add(v);     // xor 4
    v = dpp_add<0x128>(v);   // xor 8 (row_ror:8)
    v = pl16_merge(v, v);    // xor 16
    v = pl32_merge(v, v);    // xor 32
    return v;
}
// 8-value multi-reduce: lane 8j ends holding the full wave-sum of acc[j].
__device__ inline float multired8(const float* acc, bool b8) {
    float m0 = pl32_merge(acc[0], acc[4]);
    float m1 = pl32_merge(acc[1], acc[5]);
    float m2 = pl32_merge(acc[2], acc[6]);
    float m3 = pl32_merge(acc[3], acc[7]);
    float n0 = pl16_merge(m0, m2);
    float n1 = pl16_merge(m1, m3);
    float c0v = dpp_add<0x128>(n0);
    float c1v = dpp_add<0x128>(n1);
    float C = b8 ? c1v : c0v;
    C = dpp_add<0xB1>(C);
    C = dpp_add<0x4E>(C);
    C = swz_xor4_add(C);
    return C;
}

// ---------------------------------------------------------------------------
// prep: waves 0-7 factorize w (exact rank-1) -> spatial[256] + temporal[K];
// waves 8-15 build QUAD tasks: neurons 4i..4i+3 split into runs of equal
// padded row v0, each run padded to 4 slots by repeating its last neuron.
// Task = int4 { n0|n1<<16, n2|n3<<16, 0, 0 } — geometry re-derived in stage1.
// ---------------------------------------------------------------------------
__global__ __launch_bounds__(1024) void prep_kernel(
    const float* __restrict__ w, const int* __restrict__ rf,
    float* __restrict__ spatial, float* __restrict__ temporal,
    int* __restrict__ cnt, int4* __restrict__ tasks, int N)
{
    __shared__ float ss[32];
    int tid = threadIdx.x, wv = tid >> 6, l = tid & 63;
    if (tid == 0) *cnt = 0;
    __syncthreads();

    if (wv < 8) {
        for (int k = wv; k < K_; k += 8) {
            float s = 0.0f;
#pragma unroll
            for (int j = 0; j < 4; ++j) {
                float v = w[k * 256 + l + j * 64];
                s = fmaf(v, v, s);
            }
            s = allred64(s);
            if (l == 0) ss[k] = s;
        }
    } else {
        int nquad = (N + GANG - 1) / GANG;
        for (int i = tid - 512; i < nquad; i += 512) {
            int n0 = i * GANG;
            int cn = min(GANG, N - n0);
            int s = 0;
            while (s < cn) {
                int v = rf[(n0 + s) * 256] / PW;
                int e = s + 1;
                while (e < cn && rf[(n0 + e) * 256] / PW == v) ++e;
                int id0 = n0 + s;
                int id1 = n0 + min(s + 1, e - 1);
                int id2 = n0 + min(s + 2, e - 1);
                int id3 = n0 + min(s + 3, e - 1);
                int slot = atomicAdd(cnt, 1);
                tasks[slot] = make_int4(id0 | (id1 << 16), id2 | (id3 << 16), 0, 0);
                s = e;
            }
        }
    }
    __syncthreads();

    float best = -1.0f;
    int k0 = 0;
    for (int k = 0; k < K_; ++k) {
        float v = ss[k];
        if (v > best) { best = v; k0 = k; }
    }
    if (wv < 8) {
        for (int k = wv; k < K_; k += 8) {
            float d = 0.0f;
#pragma unroll
            for (int j = 0; j < 4; ++j)
                d = fmaf(w[k * 256 + l + j * 64], w[k0 * 256 + l + j * 64], d);
            d = allred64(d);
            if (l == 0) temporal[k] = d / best;
        }
    }
    if (tid < 256) spatial[tid] = w[k0 * 256 + tid];
}

// ---------------------------------------------------------------------------
// Stage 1 (quad-gather): one wave = one 4-neuron task x 25 frames.
// IDENTICAL to R17 except __launch_bounds__(256, 1): releases the register
// allocator from its default high-occupancy target (which capped VGPR at 40
// and spilled ~3.4 MB/dispatch to scratch — the R14/R15/R17 failure mode).
// Live set ~90-110 VGPR -> 4 waves/SIMD, ample for the latency-hiding this
// structure needs (R11 showed occupancy beyond ~14 waves/CU buys nothing).
// ---------------------------------------------------------------------------
__global__ __launch_bounds__(256, 1) void stage1_kernel(
    const float* __restrict__ x, const int* __restrict__ rf,
    const int4* __restrict__ tasks, const int* __restrict__ cnt,
    const float* __restrict__ spatial, float* __restrict__ y)
{
    int lane = threadIdx.x & 63;
    int wid  = threadIdx.x >> 6;

    int b    = blockIdx.x;
    int xcd  = b & (NXCD - 1);
    int half = (b >> 3) & 1;
    int tg   = b >> 4;

    int taskid = tg * 4 + wid;
    if (taskid >= *cnt) return;

    int4 d = tasks[taskid];
    int t0 = xcd * T_PER_XCD + half * T_HALF;

    int r = lane >> 2;
    int q = lane & 3;

    // --- geometry + weights, fully static (ids extracted inline) ---
    int    off[GANG];
    float4 w4[GANG];
#pragma unroll
    for (int j = 0; j < GANG; ++j) {
        int pair = (j & 2) ? d.y : d.x;
        int nj   = (j & 1) ? (pair >> 16) & 0xFFFF : pair & 0xFFFF;
        int base = rf[nj * 256];
        int v0   = base / PW;
        int r0   = v0 - RF_;
        int c0   = (base - v0 * PW) - RF_;
        int r0c  = min(max(r0, 0), H_ - RF_);
        int c0c  = min(max(c0, 0), W_ - RF_);
        off[j] = (r0c + r) * W_ + c0c + 4 * q;
        int rr = r + (r0c - r0);
        int cc = 4 * q + (c0c - c0);           // multiple of 4 on the lattice
        bool ok = (rr >= 0) & (rr < RF_) & (cc >= 0) & (cc < RF_);
        float4 wz = make_float4(0.f, 0.f, 0.f, 0.f);
        if (ok) wz = *reinterpret_cast<const float4*>(spatial + rr * RF_ + cc);
        w4[j] = wz;
    }

    // store target: lane 8j -> (w = j&3, f = j>>2); id via branchless selects
    int jmy = lane >> 3;
    int psel = (jmy & 2) ? d.y : d.x;
    int nmy  = (jmy & 1) ? (psel >> 16) & 0xFFFF : psel & 0xFFFF;
    int fmy  = jmy >> 2;
    float* ypn = y + (size_t)nmy * T_;
    bool b8 = (lane & 8) != 0;

    const float* xt = x + (size_t)t0 * HW_;

    // 12 chunks of 2 frames (local 0..23)
    for (int tt = 0; tt < 24; tt += 2) {
        const float* fA = xt + (size_t)tt * HW_;
        const float* fB = fA + HW_;
        float4 vA[GANG], vB[GANG];
#pragma unroll
        for (int j = 0; j < GANG; ++j)
            vA[j] = *reinterpret_cast<const float4*>(fA + off[j]);
#pragma unroll
        for (int j = 0; j < GANG; ++j)
            vB[j] = *reinterpret_cast<const float4*>(fB + off[j]);

        float acc[2 * GANG];
#pragma unroll
        for (int j = 0; j < GANG; ++j) {
            float u = vA[j].x * w4[j].x;
            u = fmaf(vA[j].y, w4[j].y, u);
            u = fmaf(vA[j].z, w4[j].z, u);
            acc[j] = fmaf(vA[j].w, w4[j].w, u);
            float v = vB[j].x * w4[j].x;
            v = fmaf(vB[j].y, w4[j].y, v);
            v = fmaf(vB[j].z, w4[j].z, v);
            acc[GANG + j] = fmaf(vB[j].w, w4[j].w, v);
        }
        float C = multired8(acc, b8);
        if ((lane & 7) == 0) ypn[t0 + tt + fmy] = C;
    }

    // tail frame (local 24)
    {
        const float* fA = xt + (size_t)24 * HW_;
        float acc[2 * GANG];
#pragma unroll
        for (int j = 0; j < GANG; ++j) {
            float4 v = *reinterpret_cast<const float4*>(fA + off[j]);
            float u = v.x * w4[j].x;
            u = fmaf(v.y, w4[j].y, u);
            u = fmaf(v.z, w4[j].z, u);
            acc[j] = fmaf(v.w, w4[j].w, u);
            acc[GANG + j] = 0.0f;
        }
        float C = multired8(acc, b8);
        if (((lane & 7) == 0) && fmy == 0) ypn[t0 + 24] = C;
    }
}

// ---------------------------------------------------------------------------
// Stage 2: out[n, t0] = ALPHA * softplus(BETA * (sum_k y[n,t0+k]*temporal[k]
//                                                 - GAMMA))
// ---------------------------------------------------------------------------
__global__ void stage2_kernel(const float* __restrict__ y,
                              const float* __restrict__ temporal,
                              float* __restrict__ out, int N)
{
    __shared__ float tw[K_];
    if (threadIdx.x < K_) tw[threadIdx.x] = temporal[threadIdx.x];
    __syncthreads();

    int n  = blockIdx.x;
    int t0 = threadIdx.x;
    if (n >= N || t0 >= NWIN) return;

    const float* yn = y + (size_t)n * T_;
    float g = 0.0f;
#pragma unroll
    for (int k = 0; k < K_; ++k)
        g = fmaf(yn[t0 + k], tw[k], g);

    float z = BETA * (g - GAMMA);
    float sp = fmaxf(z, 0.0f) + log1pf(expf(-fabsf(z)));
    out[n * NWIN + t0] = ALPHA * sp;
}

// ---------------------------------------------------------------------------
extern "C" void kernel_launch(void* const* d_in, const int* in_sizes, int n_in,
                              void* d_out, int out_size, void* d_ws, size_t ws_size,
                              hipStream_t stream)
{
    const float* x  = (const float*)d_in[0];  // (T, H, W) f32
    const float* w  = (const float*)d_in[1];  // (K*RF*RF,) f32
    const int*   rf = (const int*)d_in[2];    // (N, 256) i32

    int N = in_sizes[2] / (RF_ * RF_);

    // ws layout (4B words): [0,256) spatial | [256,320) temporal |
    // [320,384) cnt | [384, 384+4N) tasks (int4, cap N) | y : N*T
    float* spatial  = (float*)d_ws;
    float* temporal = spatial + 256;
    int*   cnt      = (int*)d_ws + 320;
    int4*  tasks    = (int4*)((int*)d_ws + 384);
    float* y        = (float*)d_ws + 384 + 4 * N;

    // grid sized for worst case (cnt <= N); excess waves exit on *cnt.
    int TG = (N + 3) / 4;
    prep_kernel<<<1, 1024, 0, stream>>>(w, rf, spatial, temporal, cnt, tasks, N);
    stage1_kernel<<<TG * 16, 256, 0, stream>>>(x, rf, tasks, cnt, spatial, y);
    stage2_kernel<<<N, 384, 0, stream>>>(y, temporal, (float*)d_out, N);
}